// Round 9
// baseline (162.690 us; speedup 1.0000x reference)
//
#include <hip/hip_runtime.h>

#define POOL 7
#define NCH 256
#define OUT_PER_BOX (NCH * POOL * POOL)   // 12544
#define PARTS 7
#define PART_SZ (OUT_PER_BOX / PARTS)     // 1792
#define ITERS (PART_SZ / 256)             // 7

// transposed feature maps (levels 3-5 only; level-2 stays CHW via gather)
#define HW3 16384                          // 128*128
#define HW4 4096                           // 64*64
#define HW5 1024                           // 32*32
#define T3_FLOATS (HW3 * NCH)              // 16.78 MB
#define T4_FLOATS (HW4 * NCH)              //  4.19 MB
#define T5_FLOATS (HW5 * NCH)              //  1.05 MB
#define TILES3 (HW3 / 64 * 4)              // 1024
#define TILES4 (HW4 / 64 * 4)              // 256
#define TILES5 (HW5 / 64 * 4)              // 64
#define NTILES (TILES3 + TILES4 + TILES5)  // 1344

// ---------------------------------------------------------------------------
// Kernel 1: CHW -> HWC transpose of p3/p4/p5 into workspace.
// Treated as 2D transpose [C=256][HW] -> [HW][256], 64x64 tiles via LDS.
// Both global sides fully coalesced; LDS pitch 65 -> conflict-free.
// ---------------------------------------------------------------------------
__global__ __launch_bounds__(256) void transpose_kernel(
    const float* __restrict__ p3, const float* __restrict__ p4,
    const float* __restrict__ p5, float* __restrict__ T3,
    float* __restrict__ T4, float* __restrict__ T5)
{
    __shared__ float tile[64][65];
    int bid = blockIdx.x;
    const float* src; float* dst; int HW;
    if (bid < TILES3)                { src = p3; dst = T3; HW = HW3; }
    else if (bid < TILES3 + TILES4)  { bid -= TILES3; src = p4; dst = T4; HW = HW4; }
    else                             { bid -= TILES3 + TILES4; src = p5; dst = T5; HW = HW5; }

    const int ct  = bid & 3;          // channel tile (4 x 64 = 256)
    const int hwt = bid >> 2;         // hw tile
    const int c0  = ct * 64, hw0 = hwt * 64;
    const int tx  = threadIdx.x & 63, ty = threadIdx.x >> 6;

    #pragma unroll
    for (int r = ty; r < 64; r += 4)
        tile[r][tx] = src[(size_t)(c0 + r) * HW + hw0 + tx];
    __syncthreads();
    #pragma unroll
    for (int r = ty; r < 64; r += 4)
        dst[(size_t)(hw0 + r) * 256 + c0 + tx] = tile[tx][r];
}

// ---------------------------------------------------------------------------
// Kernel 2: HWC sampling for levels 3-5 (~86% of boxes).
// Block = (box, channel-half). One (y,x) tap for 128 channels is a contiguous
// 512B run -> one float2 wave-instruction touches 8 lines (vs 64 scattered in
// CHW). Outputs buffered in LDS so global stores remain coalesced.
// ---------------------------------------------------------------------------
__global__ __launch_bounds__(256) void hwc_kernel(
    const float* __restrict__ boxes,
    const float* __restrict__ T3, const float* __restrict__ T4,
    const float* __restrict__ T5, float* __restrict__ out, int nbox)
{
    const int n  = blockIdx.x >> 1;
    const int hb = blockIdx.x & 1;            // channel half: [0,128) or [128,256)
    if (n >= nbox) return;

    const float by1 = boxes[n * 4 + 0];
    const float bx1 = boxes[n * 4 + 1];
    const float by2 = boxes[n * 4 + 2];
    const float bx2 = boxes[n * 4 + 3];
    const float h = by2 - by1;
    const float w = bx2 - bx1;
    const float lvlf = 4.0f + log2f(sqrtf(h * w) / 0.21875f);
    int lvl = (int)rintf(lvlf);               // round-half-even = jnp.round
    lvl = lvl < 2 ? 2 : (lvl > 5 ? 5 : lvl);
    if (lvl == 2) return;                     // gather2 handles level 2

    const float* T; int H;
    if (lvl == 3)      { T = T3; H = 128; }
    else if (lvl == 4) { T = T4; H = 64;  }
    else               { T = T5; H = 32;  }
    const float Hm1 = (float)(H - 1);

    __shared__ float obuf[49][132];           // 25.9 KB; pitch 132: float2-aligned,
                                              // read-phase conflicts ~4-way (free-ish)
    __shared__ int   s_y0[POOL], s_y1[POOL], s_xb[POOL], s_xcl[POOL];
    __shared__ float s_wy[POOL], s_wx[POOL], s_vy[POOL], s_vx[POOL];

    const int tid = threadIdx.x;
    if (tid < POOL) {
        const float t7 = (float)tid * (1.0f / 6.0f);

        const float yy  = (by1 + h * t7) * Hm1;
        const float y0f = floorf(yy);
        int y0 = (int)y0f; y0 = min(H - 1, max(0, y0));
        s_y0[tid] = y0;
        s_y1[tid] = min(H - 1, y0 + 1);
        s_wy[tid] = yy - y0f;                 // weight from UNCLIPPED floor
        s_vy[tid] = (yy >= 0.0f && yy <= Hm1) ? 1.0f : 0.0f;

        const float xx  = (bx1 + w * t7) * Hm1;
        const float x0f = floorf(xx);
        int x0 = (int)x0f; x0 = min(H - 1, max(0, x0));
        s_xb[tid]  = min(x0, H - 2);          // pair base: {xb, xb+1} valid
        s_xcl[tid] = (x0 == H - 1) ? 1 : 0;
        s_wx[tid]  = xx - x0f;
        s_vx[tid]  = (xx >= 0.0f && xx <= Hm1) ? 1.0f : 0.0f;
    }
    __syncthreads();

    const int wv = tid >> 6;                  // wave 0..3 -> taps wv, wv+4, ...
    const int ln = tid & 63;
    const int cb = hb * 128 + 2 * ln;         // this lane's 2 channels

    for (int pos = wv; pos < 49; pos += 4) {
        const int py = pos / 7;
        const int px = pos - py * 7;
        const int y0 = s_y0[py], y1 = s_y1[py];
        const int xb = s_xb[px], cl = s_xcl[px];

        const size_t a0 = ((size_t)(y0 * H + xb) << 8) + cb;   // *256 channels
        const size_t a1 = ((size_t)(y1 * H + xb) << 8) + cb;
        const float2 A0 = *(const float2*)&T[a0];
        const float2 A1 = *(const float2*)&T[a0 + 256];        // x = xb+1
        const float2 B0 = *(const float2*)&T[a1];
        const float2 B1 = *(const float2*)&T[a1 + 256];

        const float wy = s_wy[py], wx = s_wx[px];
        const float vv = s_vy[py] * s_vx[px];

        float2 o;
        {
            const float v00 = cl ? A1.x : A0.x;
            const float v01 = A1.x;
            const float v10 = cl ? B1.x : B0.x;
            const float v11 = B1.x;
            const float r0 = v00 + wx * (v01 - v00);
            const float r1 = v10 + wx * (v11 - v10);
            o.x = (r0 + wy * (r1 - r0)) * vv;
        }
        {
            const float v00 = cl ? A1.y : A0.y;
            const float v01 = A1.y;
            const float v10 = cl ? B1.y : B0.y;
            const float v11 = B1.y;
            const float r0 = v00 + wx * (v01 - v00);
            const float r1 = v10 + wx * (v11 - v10);
            o.y = (r0 + wy * (r1 - r0)) * vv;
        }
        *(float2*)&obuf[pos][2 * ln] = o;
    }
    __syncthreads();

    // coalesced store of this half's 128ch x 49pos block
    const size_t ob = (size_t)n * OUT_PER_BOX + (size_t)hb * 128 * 49;
    for (int i = tid; i < 128 * 49; i += 256) {
        const int c   = i / 49;
        const int pos = i - c * 49;
        out[ob + i] = obuf[pos][c];
    }
}

// ---------------------------------------------------------------------------
// Kernel 3: level-2 gather (verified R0 body; uniform early-exit otherwise).
// Level-2 boxes (~14%) read the 67 MB p2 sparsely — gather is the right tool.
// ---------------------------------------------------------------------------
__global__ __launch_bounds__(256) void gather2_kernel(
    const float* __restrict__ boxes,
    const float* __restrict__ p2,
    float* __restrict__ out, int nbox)
{
    const int n    = blockIdx.x % nbox;
    const int part = blockIdx.x / nbox;
    const int tid  = threadIdx.x;

    const float by1 = boxes[n * 4 + 0];
    const float bx1 = boxes[n * 4 + 1];
    const float by2 = boxes[n * 4 + 2];
    const float bx2 = boxes[n * 4 + 3];
    const float h = by2 - by1;
    const float w = bx2 - bx1;
    const float lvlf = 4.0f + log2f(sqrtf(h * w) / 0.21875f);
    int lvl = (int)rintf(lvlf);
    lvl = lvl < 2 ? 2 : (lvl > 5 ? 5 : lvl);
    if (lvl != 2) return;                     // uniform exit, before any barrier

    const float* fm = p2;
    const int H = 256;
    const int HW = 65536;
    const float Hm1 = 255.0f;

    __shared__ int   s_y0[POOL], s_y1[POOL], s_xb[POOL], s_xcl[POOL];
    __shared__ float s_wy[POOL], s_wx[POOL], s_vy[POOL], s_vx[POOL];

    if (tid < POOL) {
        const float t7 = (float)tid * (1.0f / 6.0f);
        const float yy  = (by1 + h * t7) * Hm1;
        const float y0f = floorf(yy);
        int y0 = (int)y0f; y0 = min(H - 1, max(0, y0));
        s_y0[tid] = y0;
        s_y1[tid] = min(H - 1, y0 + 1);
        s_wy[tid] = yy - y0f;
        s_vy[tid] = (yy >= 0.0f && yy <= Hm1) ? 1.0f : 0.0f;
        const float xx  = (bx1 + w * t7) * Hm1;
        const float x0f = floorf(xx);
        int x0 = (int)x0f; x0 = min(H - 1, max(0, x0));
        s_xb[tid]  = min(x0, H - 2);
        s_xcl[tid] = (x0 == H - 1) ? 1 : 0;
        s_wx[tid]  = xx - x0f;
        s_vx[tid]  = (xx >= 0.0f && xx <= Hm1) ? 1.0f : 0.0f;
    }
    __syncthreads();

    const size_t out_base = (size_t)n * OUT_PER_BOX + (size_t)part * PART_SZ;
    const int idx0 = part * PART_SZ + tid;

    float2 q0[ITERS], q1[ITERS];
    #pragma unroll
    for (int i = 0; i < ITERS; ++i) {
        const int idx = idx0 + i * 256;
        const int c  = idx / 49;
        const int r  = idx - c * 49;
        const int py = r / 7;
        const int px = r - py * 7;
        const float* fmc = fm + (size_t)c * HW;
        const int xb = s_xb[px];
        q0[i] = *(const float2*)(fmc + s_y0[py] * H + xb);
        q1[i] = *(const float2*)(fmc + s_y1[py] * H + xb);
    }
    #pragma unroll
    for (int i = 0; i < ITERS; ++i) {
        const int idx = idx0 + i * 256;
        const int c  = idx / 49;
        const int r  = idx - c * 49;
        const int py = r / 7;
        const int px = r - py * 7;
        const float wy = s_wy[py], wx = s_wx[px];
        const int   cl = s_xcl[px];
        const float v00 = cl ? q0[i].y : q0[i].x;
        const float v01 = q0[i].y;
        const float v10 = cl ? q1[i].y : q1[i].x;
        const float v11 = q1[i].y;
        const float r0 = v00 + wx * (v01 - v00);
        const float r1 = v10 + wx * (v11 - v10);
        out[out_base + (size_t)(i * 256 + tid)] =
            (r0 + wy * (r1 - r0)) * s_vy[py] * s_vx[px];
    }
}

// ---------------------------------------------------------------------------
// Fallback (workspace too small for the 22 MB transpose): verified R0 kernel.
// ---------------------------------------------------------------------------
__global__ __launch_bounds__(256) void roi_align_flat_kernel(
    const float* __restrict__ boxes,
    const float* __restrict__ p2, const float* __restrict__ p3,
    const float* __restrict__ p4, const float* __restrict__ p5,
    float* __restrict__ out, int nbox)
{
    const int n    = blockIdx.x % nbox;
    const int part = blockIdx.x / nbox;
    const int tid  = threadIdx.x;

    __shared__ int   s_y0[POOL], s_y1[POOL], s_xb[POOL], s_xcl[POOL];
    __shared__ float s_wy[POOL], s_wx[POOL], s_vy[POOL], s_vx[POOL];

    const float by1 = boxes[n * 4 + 0];
    const float bx1 = boxes[n * 4 + 1];
    const float by2 = boxes[n * 4 + 2];
    const float bx2 = boxes[n * 4 + 3];
    const float h = by2 - by1;
    const float w = bx2 - bx1;
    const float lvlf = 4.0f + log2f(sqrtf(h * w) / 0.21875f);
    int lvl = (int)rintf(lvlf);
    lvl = lvl < 2 ? 2 : (lvl > 5 ? 5 : lvl);

    const float* fm;
    int H;
    switch (lvl) {
        case 2:  fm = p2; H = 256; break;
        case 3:  fm = p3; H = 128; break;
        case 4:  fm = p4; H = 64;  break;
        default: fm = p5; H = 32;  break;
    }
    const float Hm1 = (float)(H - 1);

    if (tid < POOL) {
        const float t7 = (float)tid * (1.0f / 6.0f);
        const float yy  = (by1 + h * t7) * Hm1;
        const float y0f = floorf(yy);
        int y0 = (int)y0f; y0 = min(H - 1, max(0, y0));
        s_y0[tid] = y0;
        s_y1[tid] = min(H - 1, y0 + 1);
        s_wy[tid] = yy - y0f;
        s_vy[tid] = (yy >= 0.0f && yy <= Hm1) ? 1.0f : 0.0f;
        const float xx  = (bx1 + w * t7) * Hm1;
        const float x0f = floorf(xx);
        int x0 = (int)x0f; x0 = min(H - 1, max(0, x0));
        s_xb[tid]  = min(x0, H - 2);
        s_xcl[tid] = (x0 == H - 1) ? 1 : 0;
        s_wx[tid]  = xx - x0f;
        s_vx[tid]  = (xx >= 0.0f && xx <= Hm1) ? 1.0f : 0.0f;
    }
    __syncthreads();

    const size_t out_base = (size_t)n * OUT_PER_BOX + (size_t)part * PART_SZ;
    const int idx0 = part * PART_SZ + tid;
    const int HW = H * H;

    float2 q0[ITERS], q1[ITERS];
    #pragma unroll
    for (int i = 0; i < ITERS; ++i) {
        const int idx = idx0 + i * 256;
        const int c  = idx / 49;
        const int r  = idx - c * 49;
        const int py = r / 7;
        const int px = r - py * 7;
        const float* fmc = fm + (size_t)c * HW;
        const int xb = s_xb[px];
        q0[i] = *(const float2*)(fmc + s_y0[py] * H + xb);
        q1[i] = *(const float2*)(fmc + s_y1[py] * H + xb);
    }
    #pragma unroll
    for (int i = 0; i < ITERS; ++i) {
        const int idx = idx0 + i * 256;
        const int c  = idx / 49;
        const int r  = idx - c * 49;
        const int py = r / 7;
        const int px = r - py * 7;
        const float wy = s_wy[py], wx = s_wx[px];
        const int   cl = s_xcl[px];
        const float v00 = cl ? q0[i].y : q0[i].x;
        const float v01 = q0[i].y;
        const float v10 = cl ? q1[i].y : q1[i].x;
        const float v11 = q1[i].y;
        const float r0 = v00 + wx * (v01 - v00);
        const float r1 = v10 + wx * (v11 - v10);
        out[out_base + (size_t)(i * 256 + tid)] =
            (r0 + wy * (r1 - r0)) * s_vy[py] * s_vx[px];
    }
}

extern "C" void kernel_launch(void* const* d_in, const int* in_sizes, int n_in,
                              void* d_out, int out_size, void* d_ws, size_t ws_size,
                              hipStream_t stream) {
    const float* boxes = (const float*)d_in[0];
    const float* p2    = (const float*)d_in[1];
    const float* p3    = (const float*)d_in[2];
    const float* p4    = (const float*)d_in[3];
    const float* p5    = (const float*)d_in[4];
    float* out         = (float*)d_out;

    const int nbox = in_sizes[0] / 4;   // 1000
    const size_t need = (size_t)(T3_FLOATS + T4_FLOATS + T5_FLOATS) * sizeof(float); // 22 MB

    if (ws_size < need) {
        roi_align_flat_kernel<<<nbox * PARTS, 256, 0, stream>>>(
            boxes, p2, p3, p4, p5, out, nbox);
        return;
    }

    float* T3 = (float*)d_ws;
    float* T4 = T3 + T3_FLOATS;
    float* T5 = T4 + T4_FLOATS;

    transpose_kernel<<<NTILES, 256, 0, stream>>>(p3, p4, p5, T3, T4, T5);
    hwc_kernel<<<2 * nbox, 256, 0, stream>>>(boxes, T3, T4, T5, out, nbox);
    gather2_kernel<<<nbox * PARTS, 256, 0, stream>>>(boxes, p2, out, nbox);
}